// Round 1
// baseline (250.046 us; speedup 1.0000x reference)
//
#include <hip/hip_runtime.h>
#include <hip/hip_bf16.h>

// ---------------------------------------------------------------------------
// DenseCorr2d_full — FUSED corr+merge on MFMA bf16 (round 5).
//
// Single kernel per output tile (64co x 8y x 32x, 512 thr = 8 waves,
// grid 512): per 64-ch slab (4 cm):
//   1. stage tm halo 25r x 49c x 4cm -> LDS bf16 (2 parity copies, pitch 50)
//   2. corr MFMA (verified frag scheme: tp A-frags bq[8], tm 4-dword B-frags)
//      for the 10x34 halo pixel set, D -> smC [10][34][72] (zero for OOB px)
//   3. merge MFMA slab (verified scheme, nt=2 x-halves, prow = wave+dy)
// Eliminates the 67MB corrb HBM write + 43MB re-fetch and the corr kernel.
// LDS 69KB -> 2 blocks/CU x 8 waves = 16 waves/CU (2x prior occupancy).
// ws layout: Wb bf16 [9][64][256] only.
// ---------------------------------------------------------------------------

typedef __attribute__((ext_vector_type(4))) float  f32x4;
typedef __attribute__((ext_vector_type(8))) short  bf16x8;

__device__ inline unsigned int pack_bf16x2(float a, float b) {
    unsigned int ua = __builtin_bit_cast(unsigned int, a);
    unsigned int ub = __builtin_bit_cast(unsigned int, b);
    ua = (ua + 0x7fffu + ((ua >> 16) & 1u)) >> 16;   // RNE
    ub = (ub + 0x7fffu + ((ub >> 16) & 1u)) >> 16;
    return ua | (ub << 16);
}
__device__ inline unsigned short cvt1(float f) {
    unsigned int u = __builtin_bit_cast(unsigned int, f);
    return (unsigned short)((u + 0x7fffu + ((u >> 16) & 1u)) >> 16);
}

// ---------------- W transform: [co][cin][3][3] fp32 -> Wb[kk][co][256] bf16 -
__global__ __launch_bounds__(256) void wt_kernel(
    const float* __restrict__ W, unsigned short* __restrict__ Wb)
{
    int idx = (int)blockIdx.x * 256 + (int)threadIdx.x;   // < 9*64*256
    int c  = idx & 255;
    int rem = idx >> 8;
    int co = rem % 64;
    int kk = rem / 64;
    Wb[idx] = cvt1(W[(size_t)co * 2304 + (size_t)c * 9 + kk]);
}

// ---------------- Fused corr + 3x3 SAME merge conv --------------------------
__global__ __launch_bounds__(512, 4) void fused_mfma(
    const float* __restrict__ tp, const float* __restrict__ tm,
    const unsigned short* __restrict__ Wb, const float* __restrict__ bias,
    float* __restrict__ out)
{
    // corr slab for merge: [10 rows][34 cols][72 ch-pitch] shorts = 48960 B
    __shared__ __align__(16) unsigned short smC[10 * 34 * 72];
    // tm halo: [cm 4][parity 2][25 rows][50 shorts pitch] = 20000 B
    __shared__ __align__(16) unsigned short smT[4 * 2 * 25 * 50];

    const int t    = threadIdx.x;
    const int wave = t >> 6, lane = t & 63;
    const int n    = lane & 15, quad = lane >> 4;
    const int qh   = quad >> 1, jq = quad & 1;

    const int x0 = (int)blockIdx.x << 5;   // 0..96
    const int y0 = (int)blockIdx.y << 3;   // 0..120
    const int b  = (int)blockIdx.z;

    // --- corr A-frags (verified): A[m=n(=ct)][k], k=(i=2kc+qh, j=jq*8+e) ---
    bf16x8 bq[8];
    {
        const float* tpb = tp + (((size_t)(b * 16 + n)) << 8);
#pragma unroll
        for (int kc = 0; kc < 8; ++kc) {
            const float4* q = (const float4*)(tpb + (((2 * kc + qh) << 4) + (jq << 3)));
            float4 a = q[0], c4 = q[1];
            union { uint4 u; bf16x8 h; } cv;
            cv.u.x = pack_bf16x2(a.x, a.y);
            cv.u.y = pack_bf16x2(a.z, a.w);
            cv.u.z = pack_bf16x2(c4.x, c4.y);
            cv.u.w = pack_bf16x2(c4.z, c4.w);
            bq[kc] = cv.h;
        }
    }

    f32x4 acc[4][2];                       // merge accumulators [ct][x-half]
#pragma unroll
    for (int a = 0; a < 4; ++a)
#pragma unroll
        for (int q = 0; q < 2; ++q) acc[a][q] = (f32x4){0.f, 0.f, 0.f, 0.f};

#pragma unroll 1
    for (int s = 0; s < 4; ++s) {
        // ---- 1. stage tm halo for cm = 4s..4s+3 (rows y0-1..y0+23,
        //         cols x0-1..x0+47, edge-clamped; parity-shifted copy) ----
        {
            const float* tmb = tm + ((size_t)(b * 16 + (s << 2)) << 14);
#pragma unroll 1
            for (int e = t; e < 4900; e += 512) {     // 4 cm * 25 r * 49 c
                int cm  = e / 1225;
                int rem = e - 1225 * cm;
                int r   = rem / 49;
                int c   = rem - 49 * r;
                int gy = y0 - 1 + r; gy = gy < 0 ? 0 : (gy > 127 ? 127 : gy);
                int gx = x0 - 1 + c; gx = gx < 0 ? 0 : (gx > 127 ? 127 : gx);
                unsigned short h = cvt1(tmb[((size_t)cm << 14) + (gy << 7) + gx]);
                smT[((cm * 2 + 0) * 25 + r) * 50 + c] = h;
                if (c > 0)
                    smT[((cm * 2 + 1) * 25 + r) * 50 + (c - 1)] = h;
            }
        }
        __syncthreads();   // smT ready; all waves past merge(s-1) -> smC free

        // ---- 2. corr stage: 8 waves x 11 groups = 4 cm x 22 pixel-tiles ----
        {
            const unsigned* smTd = (const unsigned*)smT;
#pragma unroll 1
            for (int i = 0; i < 11; ++i) {
                const int g  = wave * 11 + i;
                const int j  = g / 22;            // cm_local 0..3
                const int tl = g - 22 * j;        // pixel tile 0..21
                const int p  = (tl << 4) + n;     // flat halo pixel 0..351
                const int pc = p < 340 ? p : 339; // clamp tail lanes (no store)
                const int py = pc / 34;
                const int px = pc - 34 * py;
                const int pl = px & 1;            // parity plane select
                // dword base: [j][pl][row=py+qh][((px-pl)/2)+jq*4]
                const int base = ((j * 2 + pl) * 25 + py + qh) * 25
                               + ((px - pl) >> 1) + (jq << 2);
                f32x4 a4 = (f32x4){0.f, 0.f, 0.f, 0.f};
#pragma unroll
                for (int kc = 0; kc < 8; ++kc) {
                    const int d = base + kc * 50;     // +2 rows per kc
                    union { uint4 u; bf16x8 h; } fr;
                    fr.u.x = smTd[d];     fr.u.y = smTd[d + 1];
                    fr.u.z = smTd[d + 2]; fr.u.w = smTd[d + 3];
                    a4 = __builtin_amdgcn_mfma_f32_16x16x32_bf16(
                        bq[kc], fr.h, a4, 0, 0, 0);
                }
                // D[row=quad*4+r = ct][col=n = pixel]; channel = j*16+quad*4+r
                const int gy = y0 - 1 + py, gx = x0 - 1 + px;
                const bool valid = ((unsigned)gy < 128u) && ((unsigned)gx < 128u);
                uint2 v;
                v.x = valid ? pack_bf16x2(a4[0], a4[1]) : 0u;  // SAME-pad zeros
                v.y = valid ? pack_bf16x2(a4[2], a4[3]) : 0u;
                if (p < 340)
                    *(uint2*)&smC[p * 72 + (j << 4) + (quad << 2)] = v;
            }
        }
        __syncthreads();   // smC ready; smT free for next slab

        // ---- 3. merge stage on slab channels c0 = 64s (verified scheme) ----
        {
            const int c0 = s << 6;
            const unsigned short* wpb = Wb + (size_t)n * 256 + c0 + (quad << 3);
            bf16x8 afc[4];
#pragma unroll
            for (int ct = 0; ct < 4; ++ct)
                afc[ct] = *(const bf16x8*)(wpb + (size_t)ct * 4096);
#pragma unroll 1
            for (int idx = 0; idx < 18; ++idx) {
                const int nidx = idx < 17 ? idx + 1 : 17;
                const int nkk = nidx >> 1, nkc = nidx & 1;
                bf16x8 afn[4];
#pragma unroll
                for (int ct = 0; ct < 4; ++ct)
                    afn[ct] = *(const bf16x8*)(wpb + (size_t)nkk * 16384
                                                   + (nkc << 5) + (size_t)ct * 4096);
                const int kk = idx >> 1, kc = idx & 1;
                const int dy = kk / 3, dx = kk - 3 * dy;
#pragma unroll
                for (int nt = 0; nt < 2; ++nt) {
                    const int prow = wave + dy;                 // wave = out row
                    const int pcol = (nt << 4) + n + dx;
                    bf16x8 bf = *(const bf16x8*)&smC[prow * 2448 + pcol * 72
                                                     + (kc << 5) + (quad << 3)];
#pragma unroll
                    for (int ct = 0; ct < 4; ++ct)
                        acc[ct][nt] = __builtin_amdgcn_mfma_f32_16x16x32_bf16(
                            afc[ct], bf, acc[ct][nt], 0, 0, 0);
                }
#pragma unroll
                for (int ct = 0; ct < 4; ++ct) afc[ct] = afn[ct];
            }
        }
        // next iteration stages smT (disjoint buffer) then barriers before
        // touching smC -> no extra sync needed here
    }

    // ---- epilogue: D[row=quad*4+r = co][col=n], + bias, fp32 out ----
#pragma unroll
    for (int ct = 0; ct < 4; ++ct) {
#pragma unroll
        for (int nt = 0; nt < 2; ++nt) {
            const int y   = y0 + wave;
            const int x   = x0 + (nt << 4) + n;
            const int co0 = (ct << 4) + (quad << 2);
            float* op = out + (((size_t)((b << 6) + co0) << 7) + y) * 128 + x;
#pragma unroll
            for (int r = 0; r < 4; ++r)
                op[(size_t)r << 14] = acc[ct][nt][r] + bias[co0 + r];
        }
    }
}

extern "C" void kernel_launch(void* const* d_in, const int* in_sizes, int n_in,
                              void* d_out, int out_size, void* d_ws, size_t ws_size,
                              hipStream_t stream)
{
    const float* tp   = (const float*)d_in[0];   // template [8,16,16,16]
    const float* tm   = (const float*)d_in[1];   // tomatch  [8,16,128,128]
    const float* Wt   = (const float*)d_in[2];   // W        [64,256,3,3]
    const float* bias = (const float*)d_in[3];   // b        [64]
    float* out = (float*)d_out;                  // [8,64,128,128] fp32

    unsigned short* Wb = (unsigned short*)d_ws;  // 294 KB

    wt_kernel<<<dim3(576), dim3(256), 0, stream>>>(Wt, Wb);
    fused_mfma<<<dim3(4, 16, 8), dim3(512), 0, stream>>>(tp, tm, Wb, bias, out);
}